// Round 1
// baseline (178.586 us; speedup 1.0000x reference)
//
#include <hip/hip_runtime.h>
#include <math.h>

constexpr int B = 32, S = 4096, H = 512;
constexpr int BDIM = 256;          // 4 waves of 64
constexpr int MAX_SPLIT = 64;      // blocks per batch row-range split

// ---------------------------------------------------------------------------
// Kernel 1: u[b,k] = sum_h h_t[b,h] * W[h,k]   (tiny: 32x512 outputs)
// ---------------------------------------------------------------------------
__global__ __launch_bounds__(BDIM) void u_kernel(const float* __restrict__ h_t,
                                                 const float* __restrict__ W,
                                                 float* __restrict__ u) {
    const int b = blockIdx.y;
    const int k = blockIdx.x * BDIM + threadIdx.x;
    __shared__ float hs[H];
    for (int i = threadIdx.x; i < H; i += BDIM) hs[i] = h_t[b * H + i];
    __syncthreads();
    float acc = 0.f;
#pragma unroll 8
    for (int h = 0; h < H; ++h) acc = fmaf(hs[h], W[h * H + k], acc);
    u[b * H + k] = acc;
}

// ---------------------------------------------------------------------------
// Kernel 2: fused single pass over context.
//   - one wave (64 lanes) per row s: lane owns h = lane*4+j (j<4) and 256+lane*4+j
//   - reads row once, writes new_buffer row (h_t at row==pos), online softmax
//     accumulates acc[8]/lane; per-wave partial (m,l,acc[512]) to workspace.
// ---------------------------------------------------------------------------
__global__ __launch_bounds__(BDIM) void flash_kernel(const float* __restrict__ ctx,
                                                     const float* __restrict__ h_t,
                                                     const float* __restrict__ u,
                                                     const int* __restrict__ posp,
                                                     float* __restrict__ newbuf,
                                                     float* __restrict__ pacc,
                                                     float* __restrict__ pml,
                                                     int nsplit) {
    const int b     = blockIdx.y;
    const int split = blockIdx.x;
    const int w     = threadIdx.x >> 6;
    const int lane  = threadIdx.x & 63;
    const int rpb   = S / nsplit;            // rows per block
    const int s0    = split * rpb;
    int pos = posp[0] % S; if (pos < 0) pos += S;

    const float4* ub = (const float4*)(u + (size_t)b * H);
    const float4 u0 = ub[lane], u1 = ub[64 + lane];
    const float4* hb = (const float4*)(h_t + (size_t)b * H);
    const float4 h0 = hb[lane], h1 = hb[64 + lane];

    float m = -INFINITY, l = 0.f;
    float4 a0 = {0.f, 0.f, 0.f, 0.f}, a1 = {0.f, 0.f, 0.f, 0.f};

    for (int s = s0 + w; s < s0 + rpb; s += 4) {
        const float4* crow = (const float4*)(ctx + ((size_t)b * S + s) * H);
        const float4 c0 = crow[lane];
        const float4 c1 = crow[64 + lane];

        float4* orow = (float4*)(newbuf + ((size_t)b * S + s) * H);
        if (s == pos) { orow[lane] = h0; orow[64 + lane] = h1; }
        else          { orow[lane] = c0; orow[64 + lane] = c1; }

        float d = c0.x * u0.x + c0.y * u0.y + c0.z * u0.z + c0.w * u0.w
                + c1.x * u1.x + c1.y * u1.y + c1.z * u1.z + c1.w * u1.w;
#pragma unroll
        for (int off = 32; off >= 1; off >>= 1) d += __shfl_xor(d, off);

        const float nm = fmaxf(m, d);
        const float sc = __expf(m - nm);   // first iter: exp(-inf)=0, acc already 0
        const float p  = __expf(d - nm);
        a0.x = a0.x * sc + p * c0.x;  a0.y = a0.y * sc + p * c0.y;
        a0.z = a0.z * sc + p * c0.z;  a0.w = a0.w * sc + p * c0.w;
        a1.x = a1.x * sc + p * c1.x;  a1.y = a1.y * sc + p * c1.y;
        a1.z = a1.z * sc + p * c1.z;  a1.w = a1.w * sc + p * c1.w;
        l = l * sc + p;
        m = nm;
    }

    const int np   = nsplit * 4;
    const int pidx = b * np + (split * 4 + w);
    float4* pa = (float4*)(pacc + (size_t)pidx * H);
    pa[lane] = a0; pa[64 + lane] = a1;
    if (lane == 0) { pml[2 * pidx] = m; pml[2 * pidx + 1] = l; }
}

// ---------------------------------------------------------------------------
// Kernel 3: combine per-wave partials -> cntx[b,:]
// ---------------------------------------------------------------------------
__global__ __launch_bounds__(BDIM) void combine_kernel(const float* __restrict__ pacc,
                                                       const float* __restrict__ pml,
                                                       float* __restrict__ cntx,
                                                       int nsplit) {
    const int b  = blockIdx.x;
    const int np = nsplit * 4;                 // <= 256
    const int t  = threadIdx.x;
    __shared__ float e[256];
    __shared__ float red[BDIM];

    // global max over partial maxima
    float mloc = -INFINITY;
    for (int p = t; p < np; p += BDIM) mloc = fmaxf(mloc, pml[2 * (b * np + p)]);
    red[t] = mloc; __syncthreads();
    for (int o = BDIM / 2; o > 0; o >>= 1) {
        if (t < o) red[t] = fmaxf(red[t], red[t + o]);
        __syncthreads();
    }
    const float M = red[0]; __syncthreads();

    // e[p] = exp(m_p - M);  L = sum e[p] * l_p
    float lloc = 0.f;
    for (int p = t; p < np; p += BDIM) {
        const float ex = __expf(pml[2 * (b * np + p)] - M);
        e[p] = ex;
        lloc += ex * pml[2 * (b * np + p) + 1];
    }
    red[t] = lloc; __syncthreads();
    for (int o = BDIM / 2; o > 0; o >>= 1) {
        if (t < o) red[t] += red[t + o];
        __syncthreads();
    }
    const float L = red[0]; __syncthreads();
    const float inv = 1.f / L;

    for (int h = t; h < H; h += BDIM) {
        float acc = 0.f;
        for (int p = 0; p < np; ++p)
            acc += e[p] * pacc[((size_t)(b * np + p)) * H + h];
        cntx[b * H + h] = acc * inv;
    }
}

// ---------------------------------------------------------------------------
extern "C" void kernel_launch(void* const* d_in, const int* in_sizes, int n_in,
                              void* d_out, int out_size, void* d_ws, size_t ws_size,
                              hipStream_t stream) {
    const float* h_t = (const float*)d_in[0];
    const float* ctx = (const float*)d_in[1];
    const float* W   = (const float*)d_in[2];
    const int*   pos = (const int*)d_in[3];

    float* out    = (float*)d_out;
    float* cntx   = out;                     // [B,H]
    float* newbuf = out + (size_t)B * H;     // [B,S,H]

    // workspace layout: u [B*H] | pacc [B*nsplit*4*H] | pml [B*nsplit*4*2]
    char*  ws = (char*)d_ws;
    float* u  = (float*)ws;
    const size_t u_bytes = (size_t)B * H * sizeof(float);

    int nsplit = MAX_SPLIT;
    while (nsplit > 1) {
        const size_t need = u_bytes
                          + (size_t)B * nsplit * 4 * H * sizeof(float)
                          + (size_t)B * nsplit * 4 * 2 * sizeof(float);
        if (need <= ws_size) break;
        nsplit >>= 1;
    }
    float* pacc = (float*)(ws + u_bytes);
    float* pml  = pacc + (size_t)B * nsplit * 4 * H;

    u_kernel<<<dim3(H / BDIM, B), BDIM, 0, stream>>>(h_t, W, u);
    flash_kernel<<<dim3(nsplit, B), BDIM, 0, stream>>>(ctx, h_t, u, pos, newbuf,
                                                       pacc, pml, nsplit);
    combine_kernel<<<dim3(B), BDIM, 0, stream>>>(pacc, pml, cntx, nsplit);
}

// Round 2
// 131.257 us; speedup vs baseline: 1.3606x; 1.3606x over previous
//
#include <hip/hip_runtime.h>
#include <math.h>

constexpr int B = 32, S = 4096, H = 512;
constexpr int BDIM = 256;          // 4 waves of 64
constexpr int MAX_SPLIT = 64;      // blocks per batch row-range split

typedef float f4 __attribute__((ext_vector_type(4)));

// ---------------------------------------------------------------------------
// Kernel 1: u[b,k] = sum_h h_t[b,h] * W[h,k]   (tiny: 32x512 outputs)
// ---------------------------------------------------------------------------
__global__ __launch_bounds__(BDIM) void u_kernel(const float* __restrict__ h_t,
                                                 const float* __restrict__ W,
                                                 float* __restrict__ u) {
    const int b = blockIdx.y;
    const int k = blockIdx.x * BDIM + threadIdx.x;
    __shared__ float hs[H];
    for (int i = threadIdx.x; i < H; i += BDIM) hs[i] = h_t[b * H + i];
    __syncthreads();
    float acc = 0.f;
#pragma unroll 8
    for (int h = 0; h < H; ++h) acc = fmaf(hs[h], W[h * H + k], acc);
    u[b * H + k] = acc;
}

// ---------------------------------------------------------------------------
// Kernel 2: fused single pass over context + block-level partial reduce.
// One wave per row; after the row loop the block's 4 waves merge (m,l,acc)
// in LDS -> ONE partial per block (nsplit per batch).
// ---------------------------------------------------------------------------
__global__ __launch_bounds__(BDIM) void flash_kernel(const float* __restrict__ ctx,
                                                     const float* __restrict__ h_t,
                                                     const float* __restrict__ u,
                                                     const int* __restrict__ posp,
                                                     float* __restrict__ newbuf,
                                                     float* __restrict__ pacc,
                                                     float* __restrict__ pml,
                                                     int nsplit) {
    const int b     = blockIdx.y;
    const int split = blockIdx.x;
    const int w     = threadIdx.x >> 6;
    const int lane  = threadIdx.x & 63;
    const int rpb   = S / nsplit;            // rows per block
    const int s0    = split * rpb;
    int pos = posp[0] % S; if (pos < 0) pos += S;

    const f4* ub = (const f4*)(u + (size_t)b * H);
    const f4 u0 = ub[lane], u1 = ub[64 + lane];
    const f4* hb = (const f4*)(h_t + (size_t)b * H);
    const f4 h0 = hb[lane], h1 = hb[64 + lane];

    float m = -INFINITY, l = 0.f;
    f4 a0 = {0.f, 0.f, 0.f, 0.f}, a1 = {0.f, 0.f, 0.f, 0.f};

#pragma unroll 2
    for (int s = s0 + w; s < s0 + rpb; s += 4) {
        const f4* crow = (const f4*)(ctx + ((size_t)b * S + s) * H);
        const f4 c0 = __builtin_nontemporal_load(crow + lane);
        const f4 c1 = __builtin_nontemporal_load(crow + 64 + lane);

        f4* orow = (f4*)(newbuf + ((size_t)b * S + s) * H);
        const f4 o0 = (s == pos) ? h0 : c0;
        const f4 o1 = (s == pos) ? h1 : c1;
        __builtin_nontemporal_store(o0, orow + lane);
        __builtin_nontemporal_store(o1, orow + 64 + lane);

        float d = c0.x * u0.x + c0.y * u0.y + c0.z * u0.z + c0.w * u0.w
                + c1.x * u1.x + c1.y * u1.y + c1.z * u1.z + c1.w * u1.w;
#pragma unroll
        for (int off = 32; off >= 1; off >>= 1) d += __shfl_xor(d, off);

        const float nm = fmaxf(m, d);
        const float sc = __expf(m - nm);   // first iter: exp(-inf)=0, acc already 0
        const float p  = __expf(d - nm);
        a0 = a0 * sc + p * c0;
        a1 = a1 * sc + p * c1;
        l = l * sc + p;
        m = nm;
    }

    // ---- block-level reduce of 4 wave partials via LDS ----
    __shared__ float lacc[4][H];
    __shared__ float lml[4][2];
    f4* dst = (f4*)&lacc[w][0];
    dst[lane] = a0; dst[64 + lane] = a1;
    if (lane == 0) { lml[w][0] = m; lml[w][1] = l; }
    __syncthreads();

    const float m0 = lml[0][0], m1 = lml[1][0], m2 = lml[2][0], m3 = lml[3][0];
    const float M  = fmaxf(fmaxf(m0, m1), fmaxf(m2, m3));
    const float e0 = __expf(m0 - M), e1 = __expf(m1 - M);
    const float e2 = __expf(m2 - M), e3 = __expf(m3 - M);

    const int t    = threadIdx.x;
    const int pidx = b * nsplit + split;
    const float ca = e0 * lacc[0][t]       + e1 * lacc[1][t]
                   + e2 * lacc[2][t]       + e3 * lacc[3][t];
    const float cb = e0 * lacc[0][256 + t] + e1 * lacc[1][256 + t]
                   + e2 * lacc[2][256 + t] + e3 * lacc[3][256 + t];
    pacc[(size_t)pidx * H + t]       = ca;
    pacc[(size_t)pidx * H + 256 + t] = cb;
    if (t == 0) {
        const float L = e0 * lml[0][1] + e1 * lml[1][1]
                      + e2 * lml[2][1] + e3 * lml[3][1];
        pml[2 * pidx] = M; pml[2 * pidx + 1] = L;
    }
}

// ---------------------------------------------------------------------------
// Kernel 3: combine per-block partials -> cntx[b,:].  grid = (B, 2);
// block handles 256 columns (one per thread).
// ---------------------------------------------------------------------------
__global__ __launch_bounds__(BDIM) void combine_kernel(const float* __restrict__ pacc,
                                                       const float* __restrict__ pml,
                                                       float* __restrict__ cntx,
                                                       int nsplit) {
    const int b    = blockIdx.x;
    const int half = blockIdx.y;
    const int t    = threadIdx.x;
    const int col  = half * 256 + t;

    __shared__ float lm[MAX_SPLIT], ll[MAX_SPLIT];
    for (int p = t; p < nsplit; p += BDIM) {
        lm[p] = pml[2 * (b * nsplit + p)];
        ll[p] = pml[2 * (b * nsplit + p) + 1];
    }
    __syncthreads();

    float M = -INFINITY;
    for (int p = 0; p < nsplit; ++p) M = fmaxf(M, lm[p]);

    float acc = 0.f, L = 0.f;
    for (int p = 0; p < nsplit; ++p) {
        const float e = __expf(lm[p] - M);
        L   = fmaf(e, ll[p], L);
        acc = fmaf(e, pacc[(size_t)(b * nsplit + p) * H + col], acc);
    }
    cntx[b * H + col] = acc / L;
}

// ---------------------------------------------------------------------------
extern "C" void kernel_launch(void* const* d_in, const int* in_sizes, int n_in,
                              void* d_out, int out_size, void* d_ws, size_t ws_size,
                              hipStream_t stream) {
    const float* h_t = (const float*)d_in[0];
    const float* ctx = (const float*)d_in[1];
    const float* W   = (const float*)d_in[2];
    const int*   pos = (const int*)d_in[3];

    float* out    = (float*)d_out;
    float* cntx   = out;                     // [B,H]
    float* newbuf = out + (size_t)B * H;     // [B,S,H]

    // workspace layout: u [B*H] | pacc [B*nsplit*H] | pml [B*nsplit*2]
    char*  ws = (char*)d_ws;
    float* u  = (float*)ws;
    const size_t u_bytes = (size_t)B * H * sizeof(float);

    int nsplit = MAX_SPLIT;
    while (nsplit > 1) {
        const size_t need = u_bytes
                          + (size_t)B * nsplit * H * sizeof(float)
                          + (size_t)B * nsplit * 2 * sizeof(float);
        if (need <= ws_size) break;
        nsplit >>= 1;
    }
    float* pacc = (float*)(ws + u_bytes);
    float* pml  = pacc + (size_t)B * nsplit * H;

    u_kernel<<<dim3(H / BDIM, B), BDIM, 0, stream>>>(h_t, W, u);
    flash_kernel<<<dim3(nsplit, B), BDIM, 0, stream>>>(ctx, h_t, u, pos, newbuf,
                                                       pacc, pml, nsplit);
    combine_kernel<<<dim3(B, 2), BDIM, 0, stream>>>(pacc, pml, cntx, nsplit);
}